// Round 15
// baseline (522.738 us; speedup 1.0000x reference)
//
#include <hip/hip_runtime.h>
#include <hip/hip_bf16.h>

#define OUTF 1024
#define NROWS 65536
#define NBR 4
#define XBROWS 66560     // rowlist/xb capacity (256-aligned branch segments)
#define NWG 4128         // 516 M-tiles(128) * 8 N-tiles(128), %8==0

typedef __attribute__((ext_vector_type(8))) short short8;
typedef __attribute__((ext_vector_type(4))) float f32x4;

__device__ inline unsigned short f2bf(float f) {
    return __builtin_bit_cast(unsigned short, (__bf16)f);
}
__device__ inline void gload_lds16(const void* g, void* l) {
    __builtin_amdgcn_global_load_lds(
        (const __attribute__((address_space(1))) void*)g,
        (__attribute__((address_space(3))) void*)l, 16, 0, 0);
}
__device__ inline short8 pack8(float4 a, float4 b) {
    short8 o;
    o[0] = (short)f2bf(a.x); o[1] = (short)f2bf(a.y);
    o[2] = (short)f2bf(a.z); o[3] = (short)f2bf(a.w);
    o[4] = (short)f2bf(b.x); o[5] = (short)f2bf(b.y);
    o[6] = (short)f2bf(b.z); o[7] = (short)f2bf(b.w);
    return o;
}
__device__ inline void seg_bases(const int* __restrict__ ws_i, int* base) {
    int s = 0;
    #pragma unroll
    for (int b = 0; b < NBR; b++) { base[b] = s; s = (s + ws_i[b] + 255) & ~255; }
}

// ws int layout: [0..3] counts, [8..11] fill positions

// Fused: blocks 0..2047 convert W (fp32 -> bf16, pre-swizzled per 128B K-window:
// wsw[br][n][kw*128+cb] = bf16(W[br][n][kw*64+((cb^((n&7)<<4))>>1)]) — R5/R6/R12
// verified zero-conflict); blocks 2048..2303 histogram feat into cnt.
__global__ void k_convw_count(const float* __restrict__ w, unsigned short* __restrict__ wsw,
                              const int* __restrict__ feat, int* __restrict__ cnt) {
    int blk = (int)blockIdx.x;
    int tid = threadIdx.x;
    if (blk < 2048) {
        int idx = blk * 256 + tid;   // 16B chunks
        int branch = idx >> 17;
        int rem = idx & 131071;
        int n = rem >> 7;
        int cb = (rem & 127) << 4;
        int kw = cb >> 7;
        int wb_ = cb & 127;
        int src = kw * 64 + ((wb_ ^ ((n & 7) << 4)) >> 1);
        const float4* s = reinterpret_cast<const float4*>(
            w + ((size_t)branch << 20) + (size_t)n * OUTF + src);
        char* dst = reinterpret_cast<char*>(wsw) + ((size_t)branch << 21) + (size_t)n * 2048 + cb;
        *reinterpret_cast<short8*>(dst) = pack8(s[0], s[1]);
    } else {
        __shared__ int lc[NBR];
        if (tid < NBR) lc[tid] = 0;
        __syncthreads();
        int r = (blk - 2048) * 256 + tid;
        int b = 26 - __clz(feat[r]);  // 32->0, 64->1, 128->2, 256->3
        atomicAdd(&lc[b], 1);
        __syncthreads();
        if (tid < NBR && lc[tid]) atomicAdd(&cnt[tid], lc[tid]);
    }
}

__global__ void k_fill(const int* __restrict__ feat, int* __restrict__ ws,
                       int* __restrict__ rowlist) {
    int base[NBR];
    seg_bases(ws, base);
    int tid = threadIdx.x;
    int lane = tid & 63;
    int r = blockIdx.x * 256 + tid;
    int b = 26 - __clz(feat[r]);
    #pragma unroll
    for (int bb = 0; bb < NBR; bb++) {
        unsigned long long mask = __ballot(b == bb);
        int leader = __ffsll((long long)mask) - 1;
        int cntw = __popcll(mask);
        int basepos = 0;
        if (lane == leader) basepos = atomicAdd(&ws[8 + bb], cntw);
        basepos = __shfl(basepos, leader < 0 ? 0 : leader);
        if (b == bb) {
            int prefix = __popcll(mask & ((1ull << lane) - 1ull));
            rowlist[base[bb] + basepos + prefix] = r;
        }
    }
}

// x fp32 -> bf16, gathered (branch-contiguous 256-aligned) + same per-window swizzle.
// 32 B out per thread (two 16B chunks, same row).
__global__ void k_convx(const float* __restrict__ x, const int* __restrict__ rowlist,
                        unsigned short* __restrict__ xb) {
    int g = (int)blockIdx.x * 512 + (int)threadIdx.x;   // 32B-out units
    int orow = g >> 6;
    int cb0 = (g & 63) << 5;
    int rl = rowlist[orow];
    if ((unsigned)rl >= NROWS) rl = 0;   // pad-gap poison -> row 0
    const int r7 = (orow & 7) << 4;
    const float* xr = x + (size_t)rl * OUTF;
    char* dr = reinterpret_cast<char*>(xb) + (size_t)orow * 2048;
    #pragma unroll
    for (int c = 0; c < 2; c++) {
        int cb = cb0 + c * 16;
        int kw = cb >> 7;
        int wb_ = cb & 127;
        int src = kw * 64 + ((wb_ ^ r7) >> 1);
        const float4* s = reinterpret_cast<const float4*>(xr + src);
        *reinterpret_cast<short8*>(dr + cb) = pack8(s[0], s[1]);
    }
}

// ===== m97-structure 128x128x64 GEMM — R12 optimum, now at 5 blocks/CU =====
// (R12 measured 193 us / MfmaUtil 30% / 0 conflicts at 3 blocks/CU.)
// Resources: 32 KB LDS x 5 = 160 KB (exact pool), 60 VGPR (<=102 for 5 w/SIMD)
// -> 20 waves/CU. Cross-block TLP is what hides the per-iter vmcnt(0) drain
// (m114); this is the only untried axis after 6 null schedule experiments.
__global__ __launch_bounds__(256, 5)
void k_gemm11(const unsigned short* __restrict__ xb,
              const unsigned short* __restrict__ wsw,
              const float* __restrict__ bias,
              const int* __restrict__ ws_i,
              const int* __restrict__ rowlist,
              float* __restrict__ out) {
    __shared__ char As[16384];
    __shared__ char Bs[16384];

    const int d = (int)blockIdx.x;
    const int work = (d & 7) * (NWG >> 3) + (d >> 3);
    const int mtile = work >> 3;
    const int ntile = work & 7;

    int bases[NBR];
    seg_bases(ws_i, bases);
    int branch = -1, lt = 0, cnt = 0, rbase = 0;
    int t_ = mtile;
    #pragma unroll
    for (int b = 0; b < NBR; b++) {
        if (branch < 0) {
            int c = ws_i[b];
            int nt = (c + 127) >> 7;
            if (t_ < nt) { branch = b; lt = t_; cnt = c; rbase = bases[b]; }
            else t_ -= nt;
        }
    }
    if (branch < 0) return;

    const int tid = (int)threadIdx.x;
    const int lane = tid & 63;
    const int wid = tid >> 6;
    const int wm = (wid & 1) << 6;   // 0/64
    const int wn = (wid >> 1) << 6;  // 0/64
    const int n0 = ntile << 7;
    const int row0 = rbase + (lt << 7);

    // staging: instr i covers dest i*4096 + tid*16 -> row i*32 + (tid>>3), chunk tid&7
    const char* aS = reinterpret_cast<const char*>(xb)
                     + (size_t)(row0 + (tid >> 3)) * 2048 + ((tid & 7) << 4);
    const char* bS = reinterpret_cast<const char*>(wsw) + ((size_t)branch << 21)
                     + (size_t)(n0 + (tid >> 3)) * 2048 + ((tid & 7) << 4);
    const int dst16 = tid << 4;

    f32x4 acc[4][4];
    #pragma unroll
    for (int i = 0; i < 4; i++)
        #pragma unroll
        for (int j = 0; j < 4; j++) acc[i][j] = (f32x4){0.f, 0.f, 0.f, 0.f};

    const int lr = lane & 15;
    const int q = lane >> 4;
    const int swz = (lane & 7) << 4;           // == (lr&7)*16
    const int arowb = (wm + lr) << 7;          // row base, 128 B/row
    const int browb = (wn + lr) << 7;

    for (int kt = 0; kt < 16; ++kt) {
        #pragma unroll
        for (int i = 0; i < 4; i++)
            gload_lds16(aS + (size_t)i * 65536 + kt * 128, As + i * 4096 + dst16);
        #pragma unroll
        for (int i = 0; i < 4; i++)
            gload_lds16(bS + (size_t)i * 65536 + kt * 128, Bs + i * 4096 + dst16);
        __syncthreads();

        #pragma unroll
        for (int ks = 0; ks < 2; ks++) {
            const int kb = (ks << 6) + (q << 4);
            short8 af[4], bf_[4];
            #pragma unroll
            for (int i = 0; i < 4; i++)
                af[i] = *reinterpret_cast<const short8*>(As + arowb + (i << 11) + (kb ^ swz));
            #pragma unroll
            for (int j = 0; j < 4; j++)
                bf_[j] = *reinterpret_cast<const short8*>(Bs + browb + (j << 11) + (kb ^ swz));
            __builtin_amdgcn_s_setprio(1);
            #pragma unroll
            for (int i = 0; i < 4; i++)
                #pragma unroll
                for (int j = 0; j < 4; j++)
                    acc[i][j] = __builtin_amdgcn_mfma_f32_16x16x32_bf16(af[i], bf_[j], acc[i][j], 0, 0, 0);
            __builtin_amdgcn_s_setprio(0);
        }
        __syncthreads();
    }

    // epilogue: + bias, scatter to original rows. C/D map: col=lane&15, row=(lane>>4)*4+reg
    const int ccol = lane & 15;
    const int crow = (lane >> 4) << 2;
    float bv[4];
    const float* bp = bias + branch * OUTF + n0 + wn;
    #pragma unroll
    for (int fn = 0; fn < 4; fn++) bv[fn] = bp[fn * 16 + ccol];
    #pragma unroll
    for (int fm = 0; fm < 4; fm++) {
        #pragma unroll
        for (int j = 0; j < 4; j++) {
            int gm = (lt << 7) + wm + fm * 16 + crow + j;
            if (gm < cnt) {
                int orow = rowlist[rbase + gm];
                float* orp = out + (size_t)orow * OUTF + n0 + wn;
                #pragma unroll
                for (int fn = 0; fn < 4; fn++)
                    orp[fn * 16 + ccol] = acc[fm][fn][j] + bv[fn];
            }
        }
    }
}

// ---------------- fallback (direct, fp32 W) if ws is too small ----------------
__global__ __launch_bounds__(256, 3)
void k_gemm_fb(const float* __restrict__ x,
               const float* __restrict__ wf,
               const float* __restrict__ bias,
               const int* __restrict__ ws_i,
               const int* __restrict__ rowlist,
               float* __restrict__ out) {
    __shared__ unsigned short As[128][72];
    __shared__ unsigned short Bs[128][72];

    int bases[NBR];
    seg_bases(ws_i, bases);
    int t = (int)blockIdx.x;
    int branch = -1, ltile = 0, cnt = 0, rbase = 0;
    #pragma unroll
    for (int b = 0; b < NBR; b++) {
        if (branch < 0) {
            int c = ws_i[b];
            int nt = (c + 127) >> 7;
            if (t < nt) { branch = b; ltile = t; cnt = c; rbase = bases[b]; }
            else t -= nt;
        }
    }
    if (branch < 0) return;

    const int tid = threadIdx.x;
    const int lane = tid & 63;
    const int wid = tid >> 6;
    const int wm = (wid & 1) << 6;
    const int wn = (wid >> 1) << 6;
    const int n0 = (int)blockIdx.y * 128;

    const int srow = tid >> 1;
    const int scol = (tid & 1) << 5;

    const int gmrow = ltile * 128 + srow;
    int grl = (gmrow < cnt) ? rowlist[rbase + gmrow] : -1;
    if (grl >= NROWS) grl = -1;
    const float* xsrc = x + (size_t)(grl < 0 ? 0 : grl) * OUTF + scol;
    const float* wfsrc = wf + ((size_t)branch << 20) + (size_t)(n0 + srow) * OUTF + scol;

    f32x4 acc[4][4];
    #pragma unroll
    for (int i = 0; i < 4; i++)
        #pragma unroll
        for (int j = 0; j < 4; j++)
            acc[i][j] = (f32x4){0.f, 0.f, 0.f, 0.f};

    for (int k0 = 0; k0 < OUTF; k0 += 64) {
        {
            unsigned short* dst = &As[srow][scol];
            if (grl >= 0) {
                const float4* s4 = reinterpret_cast<const float4*>(xsrc + k0);
                #pragma unroll
                for (int i = 0; i < 8; i += 2)
                    *reinterpret_cast<short8*>(dst + i * 4) = pack8(s4[i], s4[i + 1]);
            } else {
                short8 z = (short8){0, 0, 0, 0, 0, 0, 0, 0};
                #pragma unroll
                for (int i = 0; i < 8; i += 2) *reinterpret_cast<short8*>(dst + i * 4) = z;
            }
        }
        {
            unsigned short* dst = &Bs[srow][scol];
            const float4* s4 = reinterpret_cast<const float4*>(wfsrc + k0);
            #pragma unroll
            for (int i = 0; i < 8; i += 2)
                *reinterpret_cast<short8*>(dst + i * 4) = pack8(s4[i], s4[i + 1]);
        }
        __syncthreads();
        #pragma unroll
        for (int kk = 0; kk < 64; kk += 32) {
            const int krd = kk + (lane >> 4) * 8;
            short8 af[4], bf_[4];
            #pragma unroll
            for (int i = 0; i < 4; i++)
                af[i] = *reinterpret_cast<const short8*>(&As[wm + i * 16 + (lane & 15)][krd]);
            #pragma unroll
            for (int i = 0; i < 4; i++)
                bf_[i] = *reinterpret_cast<const short8*>(&Bs[wn + i * 16 + (lane & 15)][krd]);
            #pragma unroll
            for (int i = 0; i < 4; i++)
                #pragma unroll
                for (int j = 0; j < 4; j++)
                    acc[i][j] = __builtin_amdgcn_mfma_f32_16x16x32_bf16(af[i], bf_[j], acc[i][j], 0, 0, 0);
        }
        __syncthreads();
    }

    const int ccol = lane & 15;
    const int crow = (lane >> 4) << 2;
    float bv[4];
    const float* bp = bias + branch * OUTF + n0 + wn;
    #pragma unroll
    for (int fn = 0; fn < 4; fn++) bv[fn] = bp[fn * 16 + ccol];
    #pragma unroll
    for (int fm = 0; fm < 4; fm++) {
        #pragma unroll
        for (int j = 0; j < 4; j++) {
            int gm = ltile * 128 + wm + fm * 16 + crow + j;
            if (gm < cnt) {
                int orow = rowlist[rbase + gm];
                float* orp = out + (size_t)orow * OUTF + n0 + wn;
                #pragma unroll
                for (int fn = 0; fn < 4; fn++)
                    orp[fn * 16 + ccol] = acc[fm][fn][j] + bv[fn];
            }
        }
    }
}

extern "C" void kernel_launch(void* const* d_in, const int* in_sizes, int n_in,
                              void* d_out, int out_size, void* d_ws, size_t ws_size,
                              hipStream_t stream) {
    const float* x = (const float*)d_in[0];
    const int* feat = (const int*)d_in[1];
    const float* w = (const float*)d_in[2];
    const float* bias = (const float*)d_in[3];
    float* out = (float*)d_out;

    char* ws = (char*)d_ws;
    int* ws_i = (int*)ws;
    int* rowlist = (int*)(ws + 256);                       // 266 KB
    const size_t WSW_OFF = (size_t)512 << 10;              // 512 KB
    const size_t XB_OFF = (size_t)9 << 20;                 // 9 MB
    unsigned short* wsw = (unsigned short*)(ws + WSW_OFF); // 8 MB bf16 W (pre-swizzled)
    unsigned short* xb = (unsigned short*)(ws + XB_OFF);   // 136.3 MB bf16 x (perm+swz)
    const size_t need_full = XB_OFF + (size_t)XBROWS * 2048;

    (void)hipMemsetAsync(ws_i, 0, 64, stream);
    if (ws_size >= need_full) {
        k_convw_count<<<2048 + 256, 256, 0, stream>>>(w, wsw, feat, ws_i);
        k_fill<<<NROWS / 256, 256, 0, stream>>>(feat, ws_i, rowlist);
        k_convx<<<(XBROWS * 64) / 512, 512, 0, stream>>>(x, rowlist, xb);
        k_gemm11<<<NWG, 256, 0, stream>>>(xb, wsw, bias, ws_i, rowlist, out);
    } else {
        k_convw_count<<<256, 256, 0, stream>>>(nullptr, nullptr, feat, ws_i);  // count-only range
        k_fill<<<NROWS / 256, 256, 0, stream>>>(feat, ws_i, rowlist);
        dim3 grid(NROWS / 128 + NBR, OUTF / 128);
        k_gemm_fb<<<grid, 256, 0, stream>>>(x, w, bias, ws_i, rowlist, out);
    }
}

// Round 16
// 335.007 us; speedup vs baseline: 1.5604x; 1.5604x over previous
//
#include <hip/hip_runtime.h>
#include <hip/hip_bf16.h>

#define OUTF 1024
#define NROWS 65536
#define NBR 4
#define XBROWS 66560     // rowlist/xb capacity (256-aligned branch segments)
#define NWG 4128         // 516 M-tiles(128) * 8 N-tiles(128), %8==0

typedef __attribute__((ext_vector_type(8))) short short8;
typedef __attribute__((ext_vector_type(4))) float f32x4;

__device__ inline unsigned short f2bf(float f) {
    return __builtin_bit_cast(unsigned short, (__bf16)f);
}
__device__ inline void gload_lds16(const void* g, void* l) {
    __builtin_amdgcn_global_load_lds(
        (const __attribute__((address_space(1))) void*)g,
        (__attribute__((address_space(3))) void*)l, 16, 0, 0);
}
__device__ inline short8 pack8(float4 a, float4 b) {
    short8 o;
    o[0] = (short)f2bf(a.x); o[1] = (short)f2bf(a.y);
    o[2] = (short)f2bf(a.z); o[3] = (short)f2bf(a.w);
    o[4] = (short)f2bf(b.x); o[5] = (short)f2bf(b.y);
    o[6] = (short)f2bf(b.z); o[7] = (short)f2bf(b.w);
    return o;
}
__device__ inline void seg_bases(const int* __restrict__ ws_i, int* base) {
    int s = 0;
    #pragma unroll
    for (int b = 0; b < NBR; b++) { base[b] = s; s = (s + ws_i[b] + 255) & ~255; }
}

// ws int layout: [0..3] counts, [8..11] fill positions

// standalone count (used by fallback path)
__global__ void k_count(const int* __restrict__ feat, int* __restrict__ cnt) {
    __shared__ int lc[NBR];
    int tid = threadIdx.x;
    if (tid < NBR) lc[tid] = 0;
    __syncthreads();
    int r = blockIdx.x * 256 + tid;
    int b = 26 - __clz(feat[r]);  // 32->0, 64->1, 128->2, 256->3
    atomicAdd(&lc[b], 1);
    __syncthreads();
    if (tid < NBR && lc[tid]) atomicAdd(&cnt[tid], lc[tid]);
}

// Fused: blocks 0..2047 convert W (fp32 -> bf16, pre-swizzled per 128B K-window:
// wsw[br][n][kw*128+cb] = bf16(W[br][n][kw*64+((cb^((n&7)<<4))>>1)]) — R5/R6/R12
// verified zero-conflict); blocks 2048..2303 histogram feat into cnt.
__global__ void k_convw_count(const float* __restrict__ w, unsigned short* __restrict__ wsw,
                              const int* __restrict__ feat, int* __restrict__ cnt) {
    int blk = (int)blockIdx.x;
    int tid = threadIdx.x;
    if (blk < 2048) {
        int idx = blk * 256 + tid;   // 16B chunks
        int branch = idx >> 17;
        int rem = idx & 131071;
        int n = rem >> 7;
        int cb = (rem & 127) << 4;
        int kw = cb >> 7;
        int wb_ = cb & 127;
        int src = kw * 64 + ((wb_ ^ ((n & 7) << 4)) >> 1);
        const float4* s = reinterpret_cast<const float4*>(
            w + ((size_t)branch << 20) + (size_t)n * OUTF + src);
        char* dst = reinterpret_cast<char*>(wsw) + ((size_t)branch << 21) + (size_t)n * 2048 + cb;
        *reinterpret_cast<short8*>(dst) = pack8(s[0], s[1]);
    } else {
        __shared__ int lc[NBR];
        if (tid < NBR) lc[tid] = 0;
        __syncthreads();
        int r = (blk - 2048) * 256 + tid;
        int b = 26 - __clz(feat[r]);  // 32->0, 64->1, 128->2, 256->3
        atomicAdd(&lc[b], 1);
        __syncthreads();
        if (tid < NBR && lc[tid]) atomicAdd(&cnt[tid], lc[tid]);
    }
}

__global__ void k_fill(const int* __restrict__ feat, int* __restrict__ ws,
                       int* __restrict__ rowlist) {
    int base[NBR];
    seg_bases(ws, base);
    int tid = threadIdx.x;
    int lane = tid & 63;
    int r = blockIdx.x * 256 + tid;
    int b = 26 - __clz(feat[r]);
    #pragma unroll
    for (int bb = 0; bb < NBR; bb++) {
        unsigned long long mask = __ballot(b == bb);
        int leader = __ffsll((long long)mask) - 1;
        int cntw = __popcll(mask);
        int basepos = 0;
        if (lane == leader) basepos = atomicAdd(&ws[8 + bb], cntw);
        basepos = __shfl(basepos, leader < 0 ? 0 : leader);
        if (b == bb) {
            int prefix = __popcll(mask & ((1ull << lane) - 1ull));
            rowlist[base[bb] + basepos + prefix] = r;
        }
    }
}

// x fp32 -> bf16, gathered (branch-contiguous 256-aligned) + same per-window swizzle.
// 32 B out per thread (two 16B chunks, same row).
__global__ void k_convx(const float* __restrict__ x, const int* __restrict__ rowlist,
                        unsigned short* __restrict__ xb) {
    int g = (int)blockIdx.x * 512 + (int)threadIdx.x;   // 32B-out units
    int orow = g >> 6;
    int cb0 = (g & 63) << 5;
    int rl = rowlist[orow];
    if ((unsigned)rl >= NROWS) rl = 0;   // pad-gap poison -> row 0
    const int r7 = (orow & 7) << 4;
    const float* xr = x + (size_t)rl * OUTF;
    char* dr = reinterpret_cast<char*>(xb) + (size_t)orow * 2048;
    #pragma unroll
    for (int c = 0; c < 2; c++) {
        int cb = cb0 + c * 16;
        int kw = cb >> 7;
        int wb_ = cb & 127;
        int src = kw * 64 + ((wb_ ^ r7) >> 1);
        const float4* s = reinterpret_cast<const float4*>(xr + src);
        *reinterpret_cast<short8*>(dr + cb) = pack8(s[0], s[1]);
    }
}

// ===== m97-structure 128x128x64 GEMM — R12 optimum at safe 4 blocks/CU =====
// R12 measured 193 us / 0 conflicts at bounds(256,3); R15's bounds(256,5)
// spilled the unified VGPR+AGPR file (needs ~124 > 512/5=102): VGPR 60->48,
// WRITE 262->763 MB, 385 us. bounds(256,4) caps at 512/4=128 >= 124 -> no
// spill, guarantees 4 waves/SIMD (16 waves/CU, 128 KB of the 160 KB LDS pool).
__global__ __launch_bounds__(256, 4)
void k_gemm11(const unsigned short* __restrict__ xb,
              const unsigned short* __restrict__ wsw,
              const float* __restrict__ bias,
              const int* __restrict__ ws_i,
              const int* __restrict__ rowlist,
              float* __restrict__ out) {
    __shared__ char As[16384];
    __shared__ char Bs[16384];

    const int d = (int)blockIdx.x;
    const int work = (d & 7) * (NWG >> 3) + (d >> 3);
    const int mtile = work >> 3;
    const int ntile = work & 7;

    int bases[NBR];
    seg_bases(ws_i, bases);
    int branch = -1, lt = 0, cnt = 0, rbase = 0;
    int t_ = mtile;
    #pragma unroll
    for (int b = 0; b < NBR; b++) {
        if (branch < 0) {
            int c = ws_i[b];
            int nt = (c + 127) >> 7;
            if (t_ < nt) { branch = b; lt = t_; cnt = c; rbase = bases[b]; }
            else t_ -= nt;
        }
    }
    if (branch < 0) return;

    const int tid = (int)threadIdx.x;
    const int lane = tid & 63;
    const int wid = tid >> 6;
    const int wm = (wid & 1) << 6;   // 0/64
    const int wn = (wid >> 1) << 6;  // 0/64
    const int n0 = ntile << 7;
    const int row0 = rbase + (lt << 7);

    // staging: instr i covers dest i*4096 + tid*16 -> row i*32 + (tid>>3), chunk tid&7
    const char* aS = reinterpret_cast<const char*>(xb)
                     + (size_t)(row0 + (tid >> 3)) * 2048 + ((tid & 7) << 4);
    const char* bS = reinterpret_cast<const char*>(wsw) + ((size_t)branch << 21)
                     + (size_t)(n0 + (tid >> 3)) * 2048 + ((tid & 7) << 4);
    const int dst16 = tid << 4;

    f32x4 acc[4][4];
    #pragma unroll
    for (int i = 0; i < 4; i++)
        #pragma unroll
        for (int j = 0; j < 4; j++) acc[i][j] = (f32x4){0.f, 0.f, 0.f, 0.f};

    const int lr = lane & 15;
    const int q = lane >> 4;
    const int swz = (lane & 7) << 4;           // == (lr&7)*16
    const int arowb = (wm + lr) << 7;          // row base, 128 B/row
    const int browb = (wn + lr) << 7;

    for (int kt = 0; kt < 16; ++kt) {
        #pragma unroll
        for (int i = 0; i < 4; i++)
            gload_lds16(aS + (size_t)i * 65536 + kt * 128, As + i * 4096 + dst16);
        #pragma unroll
        for (int i = 0; i < 4; i++)
            gload_lds16(bS + (size_t)i * 65536 + kt * 128, Bs + i * 4096 + dst16);
        __syncthreads();

        #pragma unroll
        for (int ks = 0; ks < 2; ks++) {
            const int kb = (ks << 6) + (q << 4);
            short8 af[4], bf_[4];
            #pragma unroll
            for (int i = 0; i < 4; i++)
                af[i] = *reinterpret_cast<const short8*>(As + arowb + (i << 11) + (kb ^ swz));
            #pragma unroll
            for (int j = 0; j < 4; j++)
                bf_[j] = *reinterpret_cast<const short8*>(Bs + browb + (j << 11) + (kb ^ swz));
            __builtin_amdgcn_s_setprio(1);
            #pragma unroll
            for (int i = 0; i < 4; i++)
                #pragma unroll
                for (int j = 0; j < 4; j++)
                    acc[i][j] = __builtin_amdgcn_mfma_f32_16x16x32_bf16(af[i], bf_[j], acc[i][j], 0, 0, 0);
            __builtin_amdgcn_s_setprio(0);
        }
        __syncthreads();
    }

    // epilogue: + bias, scatter to original rows. C/D map: col=lane&15, row=(lane>>4)*4+reg
    const int ccol = lane & 15;
    const int crow = (lane >> 4) << 2;
    float bv[4];
    const float* bp = bias + branch * OUTF + n0 + wn;
    #pragma unroll
    for (int fn = 0; fn < 4; fn++) bv[fn] = bp[fn * 16 + ccol];
    #pragma unroll
    for (int fm = 0; fm < 4; fm++) {
        #pragma unroll
        for (int j = 0; j < 4; j++) {
            int gm = (lt << 7) + wm + fm * 16 + crow + j;
            if (gm < cnt) {
                int orow = rowlist[rbase + gm];
                float* orp = out + (size_t)orow * OUTF + n0 + wn;
                #pragma unroll
                for (int fn = 0; fn < 4; fn++)
                    orp[fn * 16 + ccol] = acc[fm][fn][j] + bv[fn];
            }
        }
    }
}

// ---------------- fallback (direct, fp32 W) if ws is too small ----------------
__global__ __launch_bounds__(256, 3)
void k_gemm_fb(const float* __restrict__ x,
               const float* __restrict__ wf,
               const float* __restrict__ bias,
               const int* __restrict__ ws_i,
               const int* __restrict__ rowlist,
               float* __restrict__ out) {
    __shared__ unsigned short As[128][72];
    __shared__ unsigned short Bs[128][72];

    int bases[NBR];
    seg_bases(ws_i, bases);
    int t = (int)blockIdx.x;
    int branch = -1, ltile = 0, cnt = 0, rbase = 0;
    #pragma unroll
    for (int b = 0; b < NBR; b++) {
        if (branch < 0) {
            int c = ws_i[b];
            int nt = (c + 127) >> 7;
            if (t < nt) { branch = b; ltile = t; cnt = c; rbase = bases[b]; }
            else t -= nt;
        }
    }
    if (branch < 0) return;

    const int tid = threadIdx.x;
    const int lane = tid & 63;
    const int wid = tid >> 6;
    const int wm = (wid & 1) << 6;
    const int wn = (wid >> 1) << 6;
    const int n0 = (int)blockIdx.y * 128;

    const int srow = tid >> 1;
    const int scol = (tid & 1) << 5;

    const int gmrow = ltile * 128 + srow;
    int grl = (gmrow < cnt) ? rowlist[rbase + gmrow] : -1;
    if (grl >= NROWS) grl = -1;
    const float* xsrc = x + (size_t)(grl < 0 ? 0 : grl) * OUTF + scol;
    const float* wfsrc = wf + ((size_t)branch << 20) + (size_t)(n0 + srow) * OUTF + scol;

    f32x4 acc[4][4];
    #pragma unroll
    for (int i = 0; i < 4; i++)
        #pragma unroll
        for (int j = 0; j < 4; j++)
            acc[i][j] = (f32x4){0.f, 0.f, 0.f, 0.f};

    for (int k0 = 0; k0 < OUTF; k0 += 64) {
        {
            unsigned short* dst = &As[srow][scol];
            if (grl >= 0) {
                const float4* s4 = reinterpret_cast<const float4*>(xsrc + k0);
                #pragma unroll
                for (int i = 0; i < 8; i += 2)
                    *reinterpret_cast<short8*>(dst + i * 4) = pack8(s4[i], s4[i + 1]);
            } else {
                short8 z = (short8){0, 0, 0, 0, 0, 0, 0, 0};
                #pragma unroll
                for (int i = 0; i < 8; i += 2) *reinterpret_cast<short8*>(dst + i * 4) = z;
            }
        }
        {
            unsigned short* dst = &Bs[srow][scol];
            const float4* s4 = reinterpret_cast<const float4*>(wfsrc + k0);
            #pragma unroll
            for (int i = 0; i < 8; i += 2)
                *reinterpret_cast<short8*>(dst + i * 4) = pack8(s4[i], s4[i + 1]);
        }
        __syncthreads();
        #pragma unroll
        for (int kk = 0; kk < 64; kk += 32) {
            const int krd = kk + (lane >> 4) * 8;
            short8 af[4], bf_[4];
            #pragma unroll
            for (int i = 0; i < 4; i++)
                af[i] = *reinterpret_cast<const short8*>(&As[wm + i * 16 + (lane & 15)][krd]);
            #pragma unroll
            for (int i = 0; i < 4; i++)
                bf_[i] = *reinterpret_cast<const short8*>(&Bs[wn + i * 16 + (lane & 15)][krd]);
            #pragma unroll
            for (int i = 0; i < 4; i++)
                #pragma unroll
                for (int j = 0; j < 4; j++)
                    acc[i][j] = __builtin_amdgcn_mfma_f32_16x16x32_bf16(af[i], bf_[j], acc[i][j], 0, 0, 0);
        }
        __syncthreads();
    }

    const int ccol = lane & 15;
    const int crow = (lane >> 4) << 2;
    float bv[4];
    const float* bp = bias + branch * OUTF + n0 + wn;
    #pragma unroll
    for (int fn = 0; fn < 4; fn++) bv[fn] = bp[fn * 16 + ccol];
    #pragma unroll
    for (int fm = 0; fm < 4; fm++) {
        #pragma unroll
        for (int j = 0; j < 4; j++) {
            int gm = ltile * 128 + wm + fm * 16 + crow + j;
            if (gm < cnt) {
                int orow = rowlist[rbase + gm];
                float* orp = out + (size_t)orow * OUTF + n0 + wn;
                #pragma unroll
                for (int fn = 0; fn < 4; fn++)
                    orp[fn * 16 + ccol] = acc[fm][fn][j] + bv[fn];
            }
        }
    }
}

extern "C" void kernel_launch(void* const* d_in, const int* in_sizes, int n_in,
                              void* d_out, int out_size, void* d_ws, size_t ws_size,
                              hipStream_t stream) {
    const float* x = (const float*)d_in[0];
    const int* feat = (const int*)d_in[1];
    const float* w = (const float*)d_in[2];
    const float* bias = (const float*)d_in[3];
    float* out = (float*)d_out;

    char* ws = (char*)d_ws;
    int* ws_i = (int*)ws;
    int* rowlist = (int*)(ws + 256);                       // 266 KB
    const size_t WSW_OFF = (size_t)512 << 10;              // 512 KB
    const size_t XB_OFF = (size_t)9 << 20;                 // 9 MB
    unsigned short* wsw = (unsigned short*)(ws + WSW_OFF); // 8 MB bf16 W (pre-swizzled)
    unsigned short* xb = (unsigned short*)(ws + XB_OFF);   // 136.3 MB bf16 x (perm+swz)
    const size_t need_full = XB_OFF + (size_t)XBROWS * 2048;

    (void)hipMemsetAsync(ws_i, 0, 64, stream);
    if (ws_size >= need_full) {
        k_convw_count<<<2048 + 256, 256, 0, stream>>>(w, wsw, feat, ws_i);
        k_fill<<<NROWS / 256, 256, 0, stream>>>(feat, ws_i, rowlist);
        k_convx<<<(XBROWS * 64) / 512, 512, 0, stream>>>(x, rowlist, xb);
        k_gemm11<<<NWG, 256, 0, stream>>>(xb, wsw, bias, ws_i, rowlist, out);
    } else {
        k_count<<<NROWS / 256, 256, 0, stream>>>(feat, ws_i);
        k_fill<<<NROWS / 256, 256, 0, stream>>>(feat, ws_i, rowlist);
        dim3 grid(NROWS / 128 + NBR, OUTF / 128);
        k_gemm_fb<<<grid, 256, 0, stream>>>(x, w, bias, ws_i, rowlist, out);
    }
}

// Round 17
// 334.748 us; speedup vs baseline: 1.5616x; 1.0008x over previous
//
#include <hip/hip_runtime.h>
#include <hip/hip_bf16.h>

#define OUTF 1024
#define NROWS 65536
#define NBR 4
#define XBROWS 66560     // rowlist/xb capacity (256-aligned branch segments)
#define NWG 4128         // 516 M-tiles(128) * 8 N-tiles(128), %8==0

typedef __attribute__((ext_vector_type(8))) short short8;
typedef __attribute__((ext_vector_type(4))) float f32x4;

__device__ inline unsigned short f2bf(float f) {
    return __builtin_bit_cast(unsigned short, (__bf16)f);
}
__device__ inline void gload_lds16(const void* g, void* l) {
    __builtin_amdgcn_global_load_lds(
        (const __attribute__((address_space(1))) void*)g,
        (__attribute__((address_space(3))) void*)l, 16, 0, 0);
}
__device__ inline short8 pack8(float4 a, float4 b) {
    short8 o;
    o[0] = (short)f2bf(a.x); o[1] = (short)f2bf(a.y);
    o[2] = (short)f2bf(a.z); o[3] = (short)f2bf(a.w);
    o[4] = (short)f2bf(b.x); o[5] = (short)f2bf(b.y);
    o[6] = (short)f2bf(b.z); o[7] = (short)f2bf(b.w);
    return o;
}
__device__ inline void seg_bases(const int* __restrict__ ws_i, int* base) {
    int s = 0;
    #pragma unroll
    for (int b = 0; b < NBR; b++) { base[b] = s; s = (s + ws_i[b] + 255) & ~255; }
}

// ws int layout: [0..3] counts, [8..11] fill positions

// standalone count (used by fallback path)
__global__ void k_count(const int* __restrict__ feat, int* __restrict__ cnt) {
    __shared__ int lc[NBR];
    int tid = threadIdx.x;
    if (tid < NBR) lc[tid] = 0;
    __syncthreads();
    int r = blockIdx.x * 256 + tid;
    int b = 26 - __clz(feat[r]);  // 32->0, 64->1, 128->2, 256->3
    atomicAdd(&lc[b], 1);
    __syncthreads();
    if (tid < NBR && lc[tid]) atomicAdd(&cnt[tid], lc[tid]);
}

// Fused: blocks 0..2047 convert W (fp32 -> bf16, pre-swizzled per 128B K-window:
// wsw[br][n][kw*128+cb] = bf16(W[br][n][kw*64+((cb^((n&7)<<4))>>1)]) — R5/R6/R12
// verified zero-conflict); blocks 2048..2303 histogram feat into cnt.
__global__ void k_convw_count(const float* __restrict__ w, unsigned short* __restrict__ wsw,
                              const int* __restrict__ feat, int* __restrict__ cnt) {
    int blk = (int)blockIdx.x;
    int tid = threadIdx.x;
    if (blk < 2048) {
        int idx = blk * 256 + tid;   // 16B chunks
        int branch = idx >> 17;
        int rem = idx & 131071;
        int n = rem >> 7;
        int cb = (rem & 127) << 4;
        int kw = cb >> 7;
        int wb_ = cb & 127;
        int src = kw * 64 + ((wb_ ^ ((n & 7) << 4)) >> 1);
        const float4* s = reinterpret_cast<const float4*>(
            w + ((size_t)branch << 20) + (size_t)n * OUTF + src);
        char* dst = reinterpret_cast<char*>(wsw) + ((size_t)branch << 21) + (size_t)n * 2048 + cb;
        *reinterpret_cast<short8*>(dst) = pack8(s[0], s[1]);
    } else {
        __shared__ int lc[NBR];
        if (tid < NBR) lc[tid] = 0;
        __syncthreads();
        int r = (blk - 2048) * 256 + tid;
        int b = 26 - __clz(feat[r]);  // 32->0, 64->1, 128->2, 256->3
        atomicAdd(&lc[b], 1);
        __syncthreads();
        if (tid < NBR && lc[tid]) atomicAdd(&cnt[tid], lc[tid]);
    }
}

__global__ void k_fill(const int* __restrict__ feat, int* __restrict__ ws,
                       int* __restrict__ rowlist) {
    int base[NBR];
    seg_bases(ws, base);
    int tid = threadIdx.x;
    int lane = tid & 63;
    int r = blockIdx.x * 256 + tid;
    int b = 26 - __clz(feat[r]);
    #pragma unroll
    for (int bb = 0; bb < NBR; bb++) {
        unsigned long long mask = __ballot(b == bb);
        int leader = __ffsll((long long)mask) - 1;
        int cntw = __popcll(mask);
        int basepos = 0;
        if (lane == leader) basepos = atomicAdd(&ws[8 + bb], cntw);
        basepos = __shfl(basepos, leader < 0 ? 0 : leader);
        if (b == bb) {
            int prefix = __popcll(mask & ((1ull << lane) - 1ull));
            rowlist[base[bb] + basepos + prefix] = r;
        }
    }
}

// x fp32 -> bf16, gathered (branch-contiguous 256-aligned) + same per-window swizzle.
// 32 B out per thread (two 16B chunks, same row).
__global__ void k_convx(const float* __restrict__ x, const int* __restrict__ rowlist,
                        unsigned short* __restrict__ xb) {
    int g = (int)blockIdx.x * 512 + (int)threadIdx.x;   // 32B-out units
    int orow = g >> 6;
    int cb0 = (g & 63) << 5;
    int rl = rowlist[orow];
    if ((unsigned)rl >= NROWS) rl = 0;   // pad-gap poison -> row 0
    const int r7 = (orow & 7) << 4;
    const float* xr = x + (size_t)rl * OUTF;
    char* dr = reinterpret_cast<char*>(xb) + (size_t)orow * 2048;
    #pragma unroll
    for (int c = 0; c < 2; c++) {
        int cb = cb0 + c * 16;
        int kw = cb >> 7;
        int wb_ = cb & 127;
        int src = kw * 64 + ((wb_ ^ r7) >> 1);
        const float4* s = reinterpret_cast<const float4*>(xr + src);
        *reinterpret_cast<short8*>(dr + cb) = pack8(s[0], s[1]);
    }
}

// ===== m97-structure 128x128x64 GEMM — measured optimum (191-195 us) =====
// bounds(256,3): the exact configuration of R12/R14's best measurements.
// (bounds-4 measured neutral; bounds-5 spilled the unified VGPR+AGPR file.)
// 4 waves (2M x 2N, 64x64 each), 32 KB LDS single-buffered, 2-barrier loop;
// both operands via global_load_lds(16B) from PRE-SWIZZLED bf16 buffers
// ([row][128B K-window], chunk c at c^(row&7)); fragment ds_read_b128 at
// (kb ^ (lane&7)*16) -> zero bank conflicts. M-tile-major XCD chunks.
__global__ __launch_bounds__(256, 3)
void k_gemm11(const unsigned short* __restrict__ xb,
              const unsigned short* __restrict__ wsw,
              const float* __restrict__ bias,
              const int* __restrict__ ws_i,
              const int* __restrict__ rowlist,
              float* __restrict__ out) {
    __shared__ char As[16384];
    __shared__ char Bs[16384];

    const int d = (int)blockIdx.x;
    const int work = (d & 7) * (NWG >> 3) + (d >> 3);
    const int mtile = work >> 3;
    const int ntile = work & 7;

    int bases[NBR];
    seg_bases(ws_i, bases);
    int branch = -1, lt = 0, cnt = 0, rbase = 0;
    int t_ = mtile;
    #pragma unroll
    for (int b = 0; b < NBR; b++) {
        if (branch < 0) {
            int c = ws_i[b];
            int nt = (c + 127) >> 7;
            if (t_ < nt) { branch = b; lt = t_; cnt = c; rbase = bases[b]; }
            else t_ -= nt;
        }
    }
    if (branch < 0) return;

    const int tid = (int)threadIdx.x;
    const int lane = tid & 63;
    const int wid = tid >> 6;
    const int wm = (wid & 1) << 6;   // 0/64
    const int wn = (wid >> 1) << 6;  // 0/64
    const int n0 = ntile << 7;
    const int row0 = rbase + (lt << 7);

    // staging: instr i covers dest i*4096 + tid*16 -> row i*32 + (tid>>3), chunk tid&7
    const char* aS = reinterpret_cast<const char*>(xb)
                     + (size_t)(row0 + (tid >> 3)) * 2048 + ((tid & 7) << 4);
    const char* bS = reinterpret_cast<const char*>(wsw) + ((size_t)branch << 21)
                     + (size_t)(n0 + (tid >> 3)) * 2048 + ((tid & 7) << 4);
    const int dst16 = tid << 4;

    f32x4 acc[4][4];
    #pragma unroll
    for (int i = 0; i < 4; i++)
        #pragma unroll
        for (int j = 0; j < 4; j++) acc[i][j] = (f32x4){0.f, 0.f, 0.f, 0.f};

    const int lr = lane & 15;
    const int q = lane >> 4;
    const int swz = (lane & 7) << 4;           // == (lr&7)*16
    const int arowb = (wm + lr) << 7;          // row base, 128 B/row
    const int browb = (wn + lr) << 7;

    for (int kt = 0; kt < 16; ++kt) {
        #pragma unroll
        for (int i = 0; i < 4; i++)
            gload_lds16(aS + (size_t)i * 65536 + kt * 128, As + i * 4096 + dst16);
        #pragma unroll
        for (int i = 0; i < 4; i++)
            gload_lds16(bS + (size_t)i * 65536 + kt * 128, Bs + i * 4096 + dst16);
        __syncthreads();

        #pragma unroll
        for (int ks = 0; ks < 2; ks++) {
            const int kb = (ks << 6) + (q << 4);
            short8 af[4], bf_[4];
            #pragma unroll
            for (int i = 0; i < 4; i++)
                af[i] = *reinterpret_cast<const short8*>(As + arowb + (i << 11) + (kb ^ swz));
            #pragma unroll
            for (int j = 0; j < 4; j++)
                bf_[j] = *reinterpret_cast<const short8*>(Bs + browb + (j << 11) + (kb ^ swz));
            __builtin_amdgcn_s_setprio(1);
            #pragma unroll
            for (int i = 0; i < 4; i++)
                #pragma unroll
                for (int j = 0; j < 4; j++)
                    acc[i][j] = __builtin_amdgcn_mfma_f32_16x16x32_bf16(af[i], bf_[j], acc[i][j], 0, 0, 0);
            __builtin_amdgcn_s_setprio(0);
        }
        __syncthreads();
    }

    // epilogue: + bias, scatter to original rows. C/D map: col=lane&15, row=(lane>>4)*4+reg
    const int ccol = lane & 15;
    const int crow = (lane >> 4) << 2;
    float bv[4];
    const float* bp = bias + branch * OUTF + n0 + wn;
    #pragma unroll
    for (int fn = 0; fn < 4; fn++) bv[fn] = bp[fn * 16 + ccol];
    #pragma unroll
    for (int fm = 0; fm < 4; fm++) {
        #pragma unroll
        for (int j = 0; j < 4; j++) {
            int gm = (lt << 7) + wm + fm * 16 + crow + j;
            if (gm < cnt) {
                int orow = rowlist[rbase + gm];
                float* orp = out + (size_t)orow * OUTF + n0 + wn;
                #pragma unroll
                for (int fn = 0; fn < 4; fn++)
                    orp[fn * 16 + ccol] = acc[fm][fn][j] + bv[fn];
            }
        }
    }
}

// ---------------- fallback (direct, fp32 W) if ws is too small ----------------
__global__ __launch_bounds__(256, 3)
void k_gemm_fb(const float* __restrict__ x,
               const float* __restrict__ wf,
               const float* __restrict__ bias,
               const int* __restrict__ ws_i,
               const int* __restrict__ rowlist,
               float* __restrict__ out) {
    __shared__ unsigned short As[128][72];
    __shared__ unsigned short Bs[128][72];

    int bases[NBR];
    seg_bases(ws_i, bases);
    int t = (int)blockIdx.x;
    int branch = -1, ltile = 0, cnt = 0, rbase = 0;
    #pragma unroll
    for (int b = 0; b < NBR; b++) {
        if (branch < 0) {
            int c = ws_i[b];
            int nt = (c + 127) >> 7;
            if (t < nt) { branch = b; ltile = t; cnt = c; rbase = bases[b]; }
            else t -= nt;
        }
    }
    if (branch < 0) return;

    const int tid = threadIdx.x;
    const int lane = tid & 63;
    const int wid = tid >> 6;
    const int wm = (wid & 1) << 6;
    const int wn = (wid >> 1) << 6;
    const int n0 = (int)blockIdx.y * 128;

    const int srow = tid >> 1;
    const int scol = (tid & 1) << 5;

    const int gmrow = ltile * 128 + srow;
    int grl = (gmrow < cnt) ? rowlist[rbase + gmrow] : -1;
    if (grl >= NROWS) grl = -1;
    const float* xsrc = x + (size_t)(grl < 0 ? 0 : grl) * OUTF + scol;
    const float* wfsrc = wf + ((size_t)branch << 20) + (size_t)(n0 + srow) * OUTF + scol;

    f32x4 acc[4][4];
    #pragma unroll
    for (int i = 0; i < 4; i++)
        #pragma unroll
        for (int j = 0; j < 4; j++)
            acc[i][j] = (f32x4){0.f, 0.f, 0.f, 0.f};

    for (int k0 = 0; k0 < OUTF; k0 += 64) {
        {
            unsigned short* dst = &As[srow][scol];
            if (grl >= 0) {
                const float4* s4 = reinterpret_cast<const float4*>(xsrc + k0);
                #pragma unroll
                for (int i = 0; i < 8; i += 2)
                    *reinterpret_cast<short8*>(dst + i * 4) = pack8(s4[i], s4[i + 1]);
            } else {
                short8 z = (short8){0, 0, 0, 0, 0, 0, 0, 0};
                #pragma unroll
                for (int i = 0; i < 8; i += 2) *reinterpret_cast<short8*>(dst + i * 4) = z;
            }
        }
        {
            unsigned short* dst = &Bs[srow][scol];
            const float4* s4 = reinterpret_cast<const float4*>(wfsrc + k0);
            #pragma unroll
            for (int i = 0; i < 8; i += 2)
                *reinterpret_cast<short8*>(dst + i * 4) = pack8(s4[i], s4[i + 1]);
        }
        __syncthreads();
        #pragma unroll
        for (int kk = 0; kk < 64; kk += 32) {
            const int krd = kk + (lane >> 4) * 8;
            short8 af[4], bf_[4];
            #pragma unroll
            for (int i = 0; i < 4; i++)
                af[i] = *reinterpret_cast<const short8*>(&As[wm + i * 16 + (lane & 15)][krd]);
            #pragma unroll
            for (int i = 0; i < 4; i++)
                bf_[i] = *reinterpret_cast<const short8*>(&Bs[wn + i * 16 + (lane & 15)][krd]);
            #pragma unroll
            for (int i = 0; i < 4; i++)
                #pragma unroll
                for (int j = 0; j < 4; j++)
                    acc[i][j] = __builtin_amdgcn_mfma_f32_16x16x32_bf16(af[i], bf_[j], acc[i][j], 0, 0, 0);
        }
        __syncthreads();
    }

    const int ccol = lane & 15;
    const int crow = (lane >> 4) << 2;
    float bv[4];
    const float* bp = bias + branch * OUTF + n0 + wn;
    #pragma unroll
    for (int fn = 0; fn < 4; fn++) bv[fn] = bp[fn * 16 + ccol];
    #pragma unroll
    for (int fm = 0; fm < 4; fm++) {
        #pragma unroll
        for (int j = 0; j < 4; j++) {
            int gm = ltile * 128 + wm + fm * 16 + crow + j;
            if (gm < cnt) {
                int orow = rowlist[rbase + gm];
                float* orp = out + (size_t)orow * OUTF + n0 + wn;
                #pragma unroll
                for (int fn = 0; fn < 4; fn++)
                    orp[fn * 16 + ccol] = acc[fm][fn][j] + bv[fn];
            }
        }
    }
}

extern "C" void kernel_launch(void* const* d_in, const int* in_sizes, int n_in,
                              void* d_out, int out_size, void* d_ws, size_t ws_size,
                              hipStream_t stream) {
    const float* x = (const float*)d_in[0];
    const int* feat = (const int*)d_in[1];
    const float* w = (const float*)d_in[2];
    const float* bias = (const float*)d_in[3];
    float* out = (float*)d_out;

    char* ws = (char*)d_ws;
    int* ws_i = (int*)ws;
    int* rowlist = (int*)(ws + 256);                       // 266 KB
    const size_t WSW_OFF = (size_t)512 << 10;              // 512 KB
    const size_t XB_OFF = (size_t)9 << 20;                 // 9 MB
    unsigned short* wsw = (unsigned short*)(ws + WSW_OFF); // 8 MB bf16 W (pre-swizzled)
    unsigned short* xb = (unsigned short*)(ws + XB_OFF);   // 136.3 MB bf16 x (perm+swz)
    const size_t need_full = XB_OFF + (size_t)XBROWS * 2048;

    (void)hipMemsetAsync(ws_i, 0, 64, stream);
    if (ws_size >= need_full) {
        k_convw_count<<<2048 + 256, 256, 0, stream>>>(w, wsw, feat, ws_i);
        k_fill<<<NROWS / 256, 256, 0, stream>>>(feat, ws_i, rowlist);
        k_convx<<<(XBROWS * 64) / 512, 512, 0, stream>>>(x, rowlist, xb);
        k_gemm11<<<NWG, 256, 0, stream>>>(xb, wsw, bias, ws_i, rowlist, out);
    } else {
        k_count<<<NROWS / 256, 256, 0, stream>>>(feat, ws_i);
        k_fill<<<NROWS / 256, 256, 0, stream>>>(feat, ws_i, rowlist);
        dim3 grid(NROWS / 128 + NBR, OUTF / 128);
        k_gemm_fb<<<grid, 256, 0, stream>>>(x, w, bias, ws_i, rowlist, out);
    }
}